// Round 10
// baseline (400.940 us; speedup 1.0000x reference)
//
#include <hip/hip_runtime.h>

// LSTMNet: SEQ=600, B=4096, IN=6, H=30, OUT=61, fp32 in/out.
// MFMA design M2: one wave = 16 batch elements; 256 single-wave blocks.
// Per gate q (i,f,g,o) and M-tile m (out-units 16m..16m+15):
//   C[q][m] (16x16) = A_h[q][m] (W_hh' | bias col 31) x B_h ([h;pad;1]^T)
//                   + A_x[q][m] (W_ih, k=0..5)        x B_x (x^T)
// via v_mfma_f32_16x16x32_f16.  C layout (m89-verified): col=lane&15=batch,
// row=(lane>>4)*4+reg=out-unit -> all 4 gates of a (unit,batch) sit in the
// SAME lane/reg across the 4 gate accumulators: c/h update is lane-local.
// Loop-invariant weights are MFMA A-operands -> AGPR residency is FREE
// (rounds 1-9 failure: VALU-read invariants get AGPR-split + per-use
// v_accvgpr_read).  h -> next-step B-fragment via 8 ds_bpermute (no LDS).

#define SEQ   600
#define BATCH 4096
#define INP   6
#define HID   30
#define NOUT  61
#define LOG2E  1.4426950408889634f
#define LOG2E2 2.8853900817779268f

typedef __fp16 f16;
typedef f16  f16x2 __attribute__((ext_vector_type(2)));
typedef f16  f16x8 __attribute__((ext_vector_type(8)));
typedef float f32x2 __attribute__((ext_vector_type(2)));
typedef float f32x4 __attribute__((ext_vector_type(4)));

__device__ __forceinline__ float rcp_(float x)  { return __builtin_amdgcn_rcpf(x); }
__device__ __forceinline__ float exp2_(float x) { return __builtin_amdgcn_exp2f(x); }
__device__ __forceinline__ unsigned cvtpk(float a, float b) {
    union { f16x2 h; unsigned u; } c;
    c.h = __builtin_amdgcn_cvt_pkrtz(a, b);
    return c.u;
}
__device__ __forceinline__ f16x8 mk8(unsigned a, unsigned b, unsigned c, unsigned d) {
    union { unsigned u[4]; f16x8 v; } x;
    x.u[0] = a; x.u[1] = b; x.u[2] = c; x.u[3] = d;
    return x.v;
}
__device__ __forceinline__ f32x2 sigm2(f32x2 x) {
    f32x2 t = x * (-LOG2E);
    f32x2 e; e.x = exp2_(t.x); e.y = exp2_(t.y);
    e = e + 1.0f;
    f32x2 r; r.x = rcp_(e.x); r.y = rcp_(e.y);
    return r;
}
__device__ __forceinline__ f32x2 tanh2(f32x2 x) {
    f32x2 t = x * LOG2E2;
    f32x2 e; e.x = exp2_(t.x); e.y = exp2_(t.y);
    e = e + 1.0f;
    f32x2 r; r.x = rcp_(e.x); r.y = rcp_(e.y);
    return 1.0f - 2.0f * r;
}

extern "C" __global__ void __launch_bounds__(64, 1)
lstm_mfma(const float* __restrict__ X,   const float* __restrict__ Wih,
          const float* __restrict__ Whh, const float* __restrict__ bih,
          const float* __restrict__ bhh, const float* __restrict__ W1,
          const float* __restrict__ b1,  const float* __restrict__ W2,
          const float* __restrict__ b2,  float* __restrict__ out)
{
    __shared__ float h2s[16][36];   // final h, f32 (padded rows)
    __shared__ float o1s[16][36];   // fc1 activations

    const int l  = threadIdx.x;       // 0..63
    const int b  = l & 15;            // batch slot (N / C-col role)
    const int g  = l >> 4;            // k-group (A/B row-group role)
    const int bg = blockIdx.x * 16 + b;   // this lane's batch element

    // ---- pack A fragments (one-time). A row = l&15 (out-unit), k = 8g+j ----
    f16x8 Ah[4][2], Ax[4][2];
    #pragma unroll
    for (int q = 0; q < 4; ++q) {
        #pragma unroll
        for (int m = 0; m < 2; ++m) {
            const int ou  = 16 * m + b;        // out-unit this lane supplies
            const bool ov = (ou < HID);
            unsigned dh[4], dx[4];
            #pragma unroll
            for (int jp = 0; jp < 4; ++jp) {
                const int k0 = 8 * g + 2 * jp, k1 = k0 + 1;
                float v0 = (ov && k0 < HID) ? Whh[(q * HID + ou) * HID + k0] : 0.f;
                float v1 = (ov && k1 < HID) ? Whh[(q * HID + ou) * HID + k1]
                         : ((ov && k1 == 31) ? (bih[q * HID + ou] + bhh[q * HID + ou]) : 0.f);
                dh[jp] = cvtpk(v0, v1);
                float w0 = (ov && k0 < INP) ? Wih[(q * HID + ou) * INP + k0] : 0.f;
                float w1 = (ov && k1 < INP) ? Wih[(q * HID + ou) * INP + k1] : 0.f;
                dx[jp] = cvtpk(w0, w1);
            }
            Ah[q][m] = mk8(dh[0], dh[1], dh[2], dh[3]);
            Ax[q][m] = mk8(dx[0], dx[1], dx[2], dx[3]);
        }
    }

    // ---- bpermute wiring: B dword d = h-pair (4g+d) ----
    // owner lane: group (2g + (d>>1)) & 3; var P0/P1 (tile0, g<2) or P2/P3 (tile1)
    const int a0 = ((((2 * g) + 0) & 3) * 16 + b) * 4;
    const int a1 = ((((2 * g) + 1) & 3) * 16 + b) * 4;
    const bool lo   = (g < 2);
    const bool isg0 = (g == 0);
    const bool isg3 = (g == 3);

    // packed h pairs: P0=(4g,4g+1) P1=(4g+2,4g+3) P2=(16+4g,..) P3=(18+4g,..)
    unsigned P0 = 0, P1 = 0, P2 = 0, P3 = 0;   // h = 0 at t = 0
    f32x2 cst[4] = {{0.f,0.f},{0.f,0.f},{0.f,0.f},{0.f,0.f}};
    f32x2 hv[4]  = {{0.f,0.f},{0.f,0.f},{0.f,0.f},{0.f,0.f}};

    // x for this lane's batch element
    f32x2 xa = *(const f32x2*)(X + (size_t)bg * INP);
    f32x2 xb = *(const f32x2*)(X + (size_t)bg * INP + 2);
    f32x2 xc = *(const f32x2*)(X + (size_t)bg * INP + 4);
    const float* pn = X + ((size_t)BATCH + bg) * INP;   // t = 1

    #define STEP(XA, XB, XC) do {                                              \
        const unsigned cv0 = cvtpk((XA).x, (XA).y);                            \
        const unsigned cv1 = cvtpk((XB).x, (XB).y);                            \
        const unsigned cv2 = cvtpk((XC).x, (XC).y);                            \
        const f16x8 Bx = mk8(isg0 ? cv0 : 0u, isg0 ? cv1 : 0u,                 \
                             isg0 ? cv2 : 0u, 0u);                             \
        const unsigned s00 = (unsigned)__builtin_amdgcn_ds_bpermute(a0,(int)P0);\
        const unsigned s01 = (unsigned)__builtin_amdgcn_ds_bpermute(a0,(int)P1);\
        const unsigned s02 = (unsigned)__builtin_amdgcn_ds_bpermute(a0,(int)P2);\
        const unsigned s03 = (unsigned)__builtin_amdgcn_ds_bpermute(a0,(int)P3);\
        const unsigned s10 = (unsigned)__builtin_amdgcn_ds_bpermute(a1,(int)P0);\
        const unsigned s11 = (unsigned)__builtin_amdgcn_ds_bpermute(a1,(int)P1);\
        const unsigned s12 = (unsigned)__builtin_amdgcn_ds_bpermute(a1,(int)P2);\
        const unsigned s13 = (unsigned)__builtin_amdgcn_ds_bpermute(a1,(int)P3);\
        const unsigned d0 = lo ? s00 : s02;                                    \
        const unsigned d1 = lo ? s01 : s03;                                    \
        const unsigned d2 = lo ? s10 : s12;                                    \
        unsigned d3 = lo ? s11 : s13;                                          \
        d3 = isg3 ? 0x3C000000u : d3;   /* k-slots (30,31) = (0, 1.0) */       \
        const f16x8 Bh = mk8(d0, d1, d2, d3);                                  \
        f32x4 Cq[4][2];                                                        \
        _Pragma("unroll")                                                      \
        for (int q = 0; q < 4; ++q) {                                          \
            _Pragma("unroll")                                                  \
            for (int m = 0; m < 2; ++m) {                                      \
                f32x4 z = {0.f, 0.f, 0.f, 0.f};                                \
                z = __builtin_amdgcn_mfma_f32_16x16x32_f16(Ah[q][m], Bh, z, 0, 0, 0); \
                Cq[q][m] = __builtin_amdgcn_mfma_f32_16x16x32_f16(Ax[q][m], Bx, z, 0, 0, 0); \
            }                                                                  \
        }                                                                      \
        _Pragma("unroll")                                                      \
        for (int m = 0; m < 2; ++m) {                                          \
            _Pragma("unroll")                                                  \
            for (int rp = 0; rp < 2; ++rp) {                                   \
                f32x2 gi = {Cq[0][m][2*rp], Cq[0][m][2*rp+1]};                 \
                f32x2 gf = {Cq[1][m][2*rp], Cq[1][m][2*rp+1]};                 \
                f32x2 gg = {Cq[2][m][2*rp], Cq[2][m][2*rp+1]};                 \
                f32x2 go = {Cq[3][m][2*rp], Cq[3][m][2*rp+1]};                 \
                const f32x2 si = sigm2(gi);                                    \
                const f32x2 sf = sigm2(gf);                                    \
                const f32x2 so = sigm2(go);                                    \
                const f32x2 tg = tanh2(gg);                                    \
                cst[m*2+rp] = sf * cst[m*2+rp] + si * tg;                      \
                hv[m*2+rp]  = so * tanh2(cst[m*2+rp]);                         \
            }                                                                  \
        }                                                                      \
        P0 = cvtpk(hv[0].x, hv[0].y);                                          \
        P1 = cvtpk(hv[1].x, hv[1].y);                                          \
        P2 = cvtpk(hv[2].x, hv[2].y);                                          \
        P3 = cvtpk(hv[3].x, hv[3].y);                                          \
    } while (0)

    for (int t = 0; t < SEQ - 1; ++t) {
        const f32x2 ya = *(const f32x2*)pn;
        const f32x2 yb = *(const f32x2*)(pn + 2);
        const f32x2 yc = *(const f32x2*)(pn + 4);
        pn += (size_t)BATCH * INP;
        STEP(xa, xb, xc);
        xa = ya; xb = yb; xc = yc;
    }
    STEP(xa, xb, xc);   // t = SEQ-1
    #undef STEP

    // ---- stash final h (f32) to LDS: lane holds units {4g..4g+3, 16+4g..} ----
    *(f32x2*)&h2s[b][4 * g]      = hv[0];
    *(f32x2*)&h2s[b][4 * g + 2]  = hv[1];
    *(f32x2*)&h2s[b][16 + 4 * g] = hv[2];
    *(f32x2*)&h2s[b][18 + 4 * g] = hv[3];
    __builtin_amdgcn_s_waitcnt(0);           // single wave: drain lgkm
    __builtin_amdgcn_sched_barrier(0);

    // ---- FC1: o1[b][u] for u = g + 4r ----
    f32x4 hr[8];
    #pragma unroll
    for (int i = 0; i < 8; ++i) hr[i] = *(const f32x4*)&h2s[b][4 * i];
    #pragma unroll
    for (int r = 0; r < 8; ++r) {
        const int u  = g + 4 * r;
        const int uc = (u < HID) ? u : (HID - 1);
        float acc = b1[uc];
        const float* wr = W1 + uc * HID;
        #pragma unroll
        for (int k = 0; k < HID; ++k) acc = fmaf(wr[k], hr[k >> 2][k & 3], acc);
        if (u < HID) o1s[b][u] = acc;
    }
    __builtin_amdgcn_s_waitcnt(0);
    __builtin_amdgcn_sched_barrier(0);

    // ---- FC2: out[bg][o] for o = g + 4r ----
    f32x4 orr[8];
    #pragma unroll
    for (int i = 0; i < 8; ++i) orr[i] = *(const f32x4*)&o1s[b][4 * i];
    #pragma unroll
    for (int r = 0; r < 16; ++r) {
        const int o  = g + 4 * r;
        const int oc = (o < NOUT) ? o : (NOUT - 1);
        float acc = b2[oc];
        const float* wr = W2 + oc * HID;
        #pragma unroll
        for (int k = 0; k < HID; ++k) acc = fmaf(wr[k], orr[k >> 2][k & 3], acc);
        if (o < NOUT) out[(size_t)bg * NOUT + o] = acc;
    }
}

extern "C" void kernel_launch(void* const* d_in, const int* in_sizes, int n_in,
                              void* d_out, int out_size, void* d_ws, size_t ws_size,
                              hipStream_t stream) {
    const float* X   = (const float*)d_in[0];
    const float* Wih = (const float*)d_in[1];
    const float* Whh = (const float*)d_in[2];
    const float* bih = (const float*)d_in[3];
    const float* bhh = (const float*)d_in[4];
    const float* W1  = (const float*)d_in[5];
    const float* b1  = (const float*)d_in[6];
    const float* W2  = (const float*)d_in[7];
    const float* b2  = (const float*)d_in[8];
    float* out = (float*)d_out;

    dim3 grid(BATCH / 16);   // 256 single-wave blocks (1 per CU)
    dim3 block(64);
    hipLaunchKernelGGL(lstm_mfma, grid, block, 0, stream,
                       X, Wih, Whh, bih, bhh, W1, b1, W2, b2, out);
}